// Round 1
// baseline (9756.715 us; speedup 1.0000x reference)
//
#include <hip/hip_runtime.h>
#include <math.h>

#define TT 512
#define BB 32
#define DD 1280

// ---------------------------------------------------------------------------
// Kernel 1: x-projection GEMM.  XP[m][n] = bias[n] + sum_k X[m][k]*Wx[n][k]
// M = T*B = 16384, N = K = D = 1280.  fp32 (no fp32 MFMA on CDNA4).
// 64x64 tile, BK=16, 256 threads, 4x4 per-thread tile, LDS stored [k][m] so
// the inner loop is 2x ds_read_b128 + 16 v_fmac per k.
// ---------------------------------------------------------------------------
__launch_bounds__(256) __global__
void xproj_gemm(const float* __restrict__ X, const float* __restrict__ Wx,
                const float* __restrict__ bias, float* __restrict__ XP)
{
    __shared__ __align__(16) float As[16][64];
    __shared__ __align__(16) float Bs[16][64];
    const int tid = threadIdx.x;
    const int n0 = blockIdx.x * 64;   // 20 n-tiles
    const int m0 = blockIdx.y * 64;   // 256 m-tiles
    const int lm = tid >> 2;          // 0..63 loader row
    const int lk = (tid & 3) << 2;    // 0,4,8,12 loader k-quad
    const int tn = tid & 15;
    const int tm = tid >> 4;

    float acc[4][4] = {};
    for (int k0 = 0; k0 < DD; k0 += 16) {
        float4 av = *(const float4*)(X  + (size_t)(m0 + lm) * DD + k0 + lk);
        float4 bv = *(const float4*)(Wx + (size_t)(n0 + lm) * DD + k0 + lk);
        __syncthreads();  // previous iter's readers done before overwrite
        As[lk + 0][lm] = av.x; As[lk + 1][lm] = av.y;
        As[lk + 2][lm] = av.z; As[lk + 3][lm] = av.w;
        Bs[lk + 0][lm] = bv.x; Bs[lk + 1][lm] = bv.y;
        Bs[lk + 2][lm] = bv.z; Bs[lk + 3][lm] = bv.w;
        __syncthreads();
#pragma unroll
        for (int k = 0; k < 16; ++k) {
            float4 a4 = *(const float4*)&As[k][tm << 2];
            float4 b4 = *(const float4*)&Bs[k][tn << 2];
            float a[4] = {a4.x, a4.y, a4.z, a4.w};
            float b[4] = {b4.x, b4.y, b4.z, b4.w};
#pragma unroll
            for (int i = 0; i < 4; ++i)
#pragma unroll
                for (int j = 0; j < 4; ++j)
                    acc[i][j] += a[i] * b[j];
        }
    }
    float4 bv = *(const float4*)(bias + n0 + (tn << 2));
    float bias4[4] = {bv.x, bv.y, bv.z, bv.w};
#pragma unroll
    for (int i = 0; i < 4; ++i) {
        float4 o;
        o.x = acc[i][0] + bias4[0];
        o.y = acc[i][1] + bias4[1];
        o.z = acc[i][2] + bias4[2];
        o.w = acc[i][3] + bias4[3];
        *(float4*)(XP + (size_t)(m0 + (tm << 2) + i) * DD + n0 + (tn << 2)) = o;
    }
}

// ---------------------------------------------------------------------------
// Kernel 2: persistent gated-Elman scan.
//   256 WGs x 256 threads.  WG w: g = w&1 (batch group: 16 batches),
//   s = w>>1 (e-slice: 10 rows of W_h, 51.2 KB fp32 in LDS -- kept <64KB).
//   Per step: h_new[b,e] = tanh(xp + sum_d h[b,d]*Wh[e,d]); y = h_new*silu(z).
//   Thread map: u = tid>>5 (8 units = 4 b-quads x 2 e-halves), p = tid&31
//   (32-way d-split, d = p*4 + k*128).  h read straight from global (L2);
//   5-round __shfl_xor all-reduce over p; lanes p<20 finalize one output each.
//   Sync: per-WG monotonic counters + agent release/acquire fences; ping-pong
//   h buffers => 1 wait/step is provably race-free (cnt_w >= t-1 implies w is
//   done READING buffer t&1 from step t-1, so overwriting it is safe).
//   256 blocks, 51.2KB LDS -> all co-resident by capacity; spin cannot hang.
// ---------------------------------------------------------------------------
__launch_bounds__(256, 1) __global__
void gated_scan(const float* __restrict__ XP, const float* __restrict__ Z,
                const float* __restrict__ Wh, float* __restrict__ OUT,
                float* __restrict__ hbuf, unsigned* __restrict__ cnt)
{
    const int w  = blockIdx.x;
    const int g  = w & 1;      // batch group
    const int s  = w >> 1;     // e-slice 0..127
    const int b0 = g << 4;     // first batch of group
    const int e0 = s * 10;     // first W_h row of slice
    const int tid = threadIdx.x;
    const int u  = tid >> 5;   // 0..7
    const int p  = tid & 31;   // d-split lane
    const int bg = u >> 1;     // 0..3  -> batches b0+4*bg..+3
    const int eg = u & 1;      // 0..1  -> e-rows eg*5..+4

    __shared__ __align__(16) float Wlds[10 * DD];   // 51.2 KB

    for (int i = tid; i < 10 * DD / 4; i += 256)
        ((float4*)Wlds)[i] = ((const float4*)(Wh + (size_t)e0 * DD))[i];

    // output owned by this lane when p < 20
    const int  o   = p;
    const int  bb  = b0 + (bg << 2) + o / 5;
    const int  ee  = e0 + eg * 5 + o % 5;
    const bool fin = (p < 20);

    for (int t = 1; t <= TT; ++t) {
        // prefetch xp/z for this step (independent of h -> overlaps the wait)
        const size_t oidx = ((size_t)(t - 1) * BB + bb) * DD + ee;
        float xpv = 0.f, zv = 0.f;
        if (fin) { xpv = XP[oidx]; zv = Z[oidx]; }

        // wait until every group member has published h_{t-1}
        if (tid < 64) {
            const unsigned tgt = (unsigned)(t - 1);
            unsigned* c1 = cnt + ((tid << 1) | g);
            unsigned* c2 = cnt + (((tid + 64) << 1) | g);
            while (__hip_atomic_load(c1, __ATOMIC_RELAXED,
                                     __HIP_MEMORY_SCOPE_AGENT) < tgt) {}
            while (__hip_atomic_load(c2, __ATOMIC_RELAXED,
                                     __HIP_MEMORY_SCOPE_AGENT) < tgt) {}
            __builtin_amdgcn_fence(__ATOMIC_ACQUIRE, "agent"); // inv L1/L2
        }
        __syncthreads();

        const float* hsrc = hbuf + (size_t)((t - 1) & 1) * BB * DD;
        float acc[4][5] = {};
#pragma unroll
        for (int k = 0; k < 10; ++k) {
            const int d = (p << 2) + (k << 7);   // p*4 + k*128, covers 0..1279
            float4 h4[4], w4[5];
#pragma unroll
            for (int i = 0; i < 4; ++i)
                h4[i] = *(const float4*)(hsrc +
                         (size_t)(b0 + (bg << 2) + i) * DD + d);
#pragma unroll
            for (int j = 0; j < 5; ++j)
                w4[j] = *(const float4*)&Wlds[(eg * 5 + j) * DD + d];
#pragma unroll
            for (int i = 0; i < 4; ++i)
#pragma unroll
                for (int j = 0; j < 5; ++j)
                    acc[i][j] += h4[i].x * w4[j].x + h4[i].y * w4[j].y
                               + h4[i].z * w4[j].z + h4[i].w * w4[j].w;
        }

        // all-reduce over p (lane bits 0..4; bit5 = e-half, untouched)
#pragma unroll
        for (int m = 16; m >= 1; m >>= 1)
#pragma unroll
            for (int i = 0; i < 4; ++i)
#pragma unroll
                for (int j = 0; j < 5; ++j)
                    acc[i][j] += __shfl_xor(acc[i][j], m, 64);

        if (fin) {
            float sum = acc[0][0];
#pragma unroll
            for (int q = 1; q < 20; ++q)
                sum = (o == q) ? acc[q / 5][q % 5] : sum;
            const float hn = tanhf(xpv + sum);
            const float sg = zv / (1.0f + __expf(-zv));
            OUT[oidx] = hn * sg;
            hbuf[(size_t)(t & 1) * BB * DD + (size_t)bb * DD + ee] = hn;
            if (t == TT)
                OUT[(size_t)TT * BB * DD + (size_t)bb * DD + ee] = hn;
        }
        __syncthreads();                       // drains vmem before barrier
        if (tid == 0) {
            __builtin_amdgcn_fence(__ATOMIC_RELEASE, "agent");  // wb L2->LLC
            __hip_atomic_store(cnt + w, (unsigned)t, __ATOMIC_RELAXED,
                               __HIP_MEMORY_SCOPE_AGENT);
        }
    }
}

// ---------------------------------------------------------------------------
extern "C" void kernel_launch(void* const* d_in, const int* in_sizes, int n_in,
                              void* d_out, int out_size, void* d_ws, size_t ws_size,
                              hipStream_t stream) {
    const float* x    = (const float*)d_in[0];  // [T,B,D]
    const float* z    = (const float*)d_in[1];  // [T,B,D]
    const float* h0   = (const float*)d_in[2];  // [B,D]
    const float* Wx   = (const float*)d_in[3];  // [D,D]
    const float* Wh   = (const float*)d_in[4];  // [D,D]
    const float* bias = (const float*)d_in[5];  // [D]
    float* out = (float*)d_out;

    // ws layout: xp (83.9 MB) | hbuf ping-pong (320 KB) | counters (1 KB)
    float*    xp   = (float*)d_ws;
    float*    hbuf = xp + (size_t)TT * BB * DD;
    unsigned* cnt  = (unsigned*)(hbuf + 2 * BB * DD);

    // ws is re-poisoned 0xAA before every launch: re-init counters + h_0
    hipMemsetAsync(cnt, 0, 256 * sizeof(unsigned), stream);
    hipMemcpyAsync(hbuf, h0, (size_t)BB * DD * sizeof(float),
                   hipMemcpyDeviceToDevice, stream);

    dim3 ggrid(DD / 64, (TT * BB) / 64);  // (20, 256)
    xproj_gemm<<<ggrid, 256, 0, stream>>>(x, Wx, bias, xp);
    gated_scan<<<256, 256, 0, stream>>>(xp, z, Wh, out, hbuf, cnt);
}

// Round 3
// 5262.862 us; speedup vs baseline: 1.8539x; 1.8539x over previous
//
#include <hip/hip_runtime.h>
#include <math.h>

#define TT 512
#define BB 32
#define DD 1280

// ---------------------------------------------------------------------------
// Kernel 1: x-projection GEMM.  XP[m][n] = bias[n] + sum_k X[m][k]*Wx[n][k]
// M = T*B = 16384, N = K = D = 1280.  fp32 (no fp32 MFMA on CDNA4).
// Unchanged from R1 (~830 us; revisit once the scan is fixed).
// ---------------------------------------------------------------------------
__launch_bounds__(256) __global__
void xproj_gemm(const float* __restrict__ X, const float* __restrict__ Wx,
                const float* __restrict__ bias, float* __restrict__ XP)
{
    __shared__ __align__(16) float As[16][64];
    __shared__ __align__(16) float Bs[16][64];
    const int tid = threadIdx.x;
    const int n0 = blockIdx.x * 64;
    const int m0 = blockIdx.y * 64;
    const int lm = tid >> 2;
    const int lk = (tid & 3) << 2;
    const int tn = tid & 15;
    const int tm = tid >> 4;

    float acc[4][4] = {};
    for (int k0 = 0; k0 < DD; k0 += 16) {
        float4 av = *(const float4*)(X  + (size_t)(m0 + lm) * DD + k0 + lk);
        float4 bv = *(const float4*)(Wx + (size_t)(n0 + lm) * DD + k0 + lk);
        __syncthreads();
        As[lk + 0][lm] = av.x; As[lk + 1][lm] = av.y;
        As[lk + 2][lm] = av.z; As[lk + 3][lm] = av.w;
        Bs[lk + 0][lm] = bv.x; Bs[lk + 1][lm] = bv.y;
        Bs[lk + 2][lm] = bv.z; Bs[lk + 3][lm] = bv.w;
        __syncthreads();
#pragma unroll
        for (int k = 0; k < 16; ++k) {
            float4 a4 = *(const float4*)&As[k][tm << 2];
            float4 b4 = *(const float4*)&Bs[k][tn << 2];
            float a[4] = {a4.x, a4.y, a4.z, a4.w};
            float b[4] = {b4.x, b4.y, b4.z, b4.w};
#pragma unroll
            for (int i = 0; i < 4; ++i)
#pragma unroll
                for (int j = 0; j < 4; ++j)
                    acc[i][j] += a[i] * b[j];
        }
    }
    float4 bv = *(const float4*)(bias + n0 + (tn << 2));
    float bias4[4] = {bv.x, bv.y, bv.z, bv.w};
#pragma unroll
    for (int i = 0; i < 4; ++i) {
        float4 o;
        o.x = acc[i][0] + bias4[0];
        o.y = acc[i][1] + bias4[1];
        o.z = acc[i][2] + bias4[2];
        o.w = acc[i][3] + bias4[3];
        *(float4*)(XP + (size_t)(m0 + (tm << 2) + i) * DD + n0 + (tn << 2)) = o;
    }
}

// ---------------------------------------------------------------------------
// Device-scope (LLC-coherent) access helpers.  __hip_atomic_* with AGENT
// scope compile to global_load/store ... sc1: they bypass the per-XCD L1/L2
// entirely and are served by the device coherence point.  R1 validated this
// mechanism on HW (counters).  R2's bug: hist READS used plain cached loads,
// which can hit a pre-write stale copy in the consumer XCD's L2 (no
// cross-XCD coherence protocol).  Fix: hist never touches L1/L2, on either
// side.  No cache-wide wb/inv instructions anywhere.
// ---------------------------------------------------------------------------
__device__ __forceinline__ float4 ld_agent_f4(const float* p) {
    const unsigned long long* q = (const unsigned long long*)p;
    unsigned long long a = __hip_atomic_load(q + 0, __ATOMIC_RELAXED,
                                             __HIP_MEMORY_SCOPE_AGENT);
    unsigned long long b = __hip_atomic_load(q + 1, __ATOMIC_RELAXED,
                                             __HIP_MEMORY_SCOPE_AGENT);
    float4 v;
    v.x = __uint_as_float((unsigned)a);
    v.y = __uint_as_float((unsigned)(a >> 32));
    v.z = __uint_as_float((unsigned)b);
    v.w = __uint_as_float((unsigned)(b >> 32));
    return v;
}

// ---------------------------------------------------------------------------
// Kernel 2: persistent gated-Elman scan, write-once h history, LLC-coherent.
//   4 batch-groups x 8 batches; 64 WGs/group, each owns 20 W_h rows
//   (102.4 KB LDS -> exactly 1 WG/CU, grid 256 = CU count, all co-resident
//   so spins cannot deadlock).
//   hist[t] is written once (sc1 write-through) and read only with sc1
//   loads -> no L1/L2 copy of hist ever exists -> no stale-line hazard.
//   Release: h stores (sc1, vmcnt-tracked) -> s_waitcnt 0 + __syncthreads
//   (drains to coherence point) -> tid0 publishes per-WG counter (sc1).
//   Acquire: peers poll counters (sc1); __syncthreads orders poll before
//   the step's h loads.
//   Thread map: u=tid>>5 (2 batch-halves x 4 e-quints), p=tid&31 (d-split,
//   d=4p+128k).  All 40 h float4 are preloaded per step (160 VGPRs; we're
//   pinned at 1 wave/SIMD by LDS anyway) so LLC latency is paid once.
// ---------------------------------------------------------------------------
__launch_bounds__(256, 1) __global__
void gated_scan(const float* __restrict__ XP, const float* __restrict__ Z,
                const float* __restrict__ Wh, float* __restrict__ OUT,
                float* __restrict__ hist, unsigned* __restrict__ cnt)
{
    const int w   = blockIdx.x;
    const int g   = w >> 6;       // batch group 0..3
    const int idx = w & 63;       // e-slice within group
    const int b0  = g << 3;       // first of 8 batches
    const int e0  = idx * 20;     // first of 20 W_h rows
    const int tid = threadIdx.x;
    const int u   = tid >> 5;     // 0..7
    const int p   = tid & 31;     // d-split lane
    const int bh  = u >> 2;       // 0..1 -> batches b0+4*bh+i
    const int eq  = u & 3;        // 0..3 -> e-rows e0+5*eq+j

    __shared__ __align__(16) float Wlds[20 * DD];   // 102.4 KB

    for (int i = tid; i < 20 * DD / 4; i += 256)
        ((float4*)Wlds)[i] = ((const float4*)(Wh + (size_t)e0 * DD))[i];
    __syncthreads();

    const int  o   = p;
    const bool fin = (p < 20);
    const int  bb  = b0 + (bh << 2) + o / 5;
    const int  ee  = e0 + eq * 5 + o % 5;

    for (int t = 1; t <= TT; ++t) {
        // prefetch xp/z (independent of h -> overlaps the wait)
        const size_t oidx = ((size_t)(t - 1) * BB + bb) * DD + ee;
        float xpv = 0.f, zv = 0.f;
        if (fin) { xpv = XP[oidx]; zv = Z[oidx]; }

        // wait for all 64 group peers to have published h_{t-1}
        if (tid < 64) {
            const unsigned  tgt = (unsigned)(t - 1);
            const unsigned* c   = cnt + (g << 6) + tid;
            while (__hip_atomic_load(c, __ATOMIC_RELAXED,
                                     __HIP_MEMORY_SCOPE_AGENT) < tgt) {}
        }
        __syncthreads();

        const float* hsrc = hist + (size_t)(t - 1) * BB * DD;

        // preload the whole step's h (coherent, LLC-served)
        float4 h4[10][4];
#pragma unroll
        for (int k = 0; k < 10; ++k) {
            const int d = (p << 2) + (k << 7);   // 4p + 128k
#pragma unroll
            for (int i = 0; i < 4; ++i)
                h4[k][i] = ld_agent_f4(hsrc +
                            (size_t)(b0 + (bh << 2) + i) * DD + d);
        }

        float acc[4][5] = {};
#pragma unroll
        for (int k = 0; k < 10; ++k) {
            const int d = (p << 2) + (k << 7);
            float4 w4[5];
#pragma unroll
            for (int j = 0; j < 5; ++j)
                w4[j] = *(const float4*)&Wlds[(eq * 5 + j) * DD + d];
#pragma unroll
            for (int i = 0; i < 4; ++i)
#pragma unroll
                for (int j = 0; j < 5; ++j)
                    acc[i][j] += h4[k][i].x * w4[j].x + h4[k][i].y * w4[j].y
                               + h4[k][i].z * w4[j].z + h4[k][i].w * w4[j].w;
        }

        // all-reduce over the 32 d-split lanes (bit5 = unit bit, untouched)
#pragma unroll
        for (int m = 16; m >= 1; m >>= 1)
#pragma unroll
            for (int i = 0; i < 4; ++i)
#pragma unroll
                for (int j = 0; j < 5; ++j)
                    acc[i][j] += __shfl_xor(acc[i][j], m, 64);

        if (fin) {
            float sum = acc[0][0];
#pragma unroll
            for (int q = 1; q < 20; ++q)
                sum = (o == q) ? acc[q / 5][q % 5] : sum;
            const float hn = tanhf(xpv + sum);
            const float sg = zv / (1.0f + __expf(-zv));
            OUT[oidx] = hn * sg;
            __hip_atomic_store(hist + (size_t)t * BB * DD +
                               (size_t)bb * DD + ee, hn,
                               __ATOMIC_RELAXED, __HIP_MEMORY_SCOPE_AGENT);
            if (t == TT)
                OUT[(size_t)TT * BB * DD + (size_t)bb * DD + ee] = hn;
        }
        // drain the sc1 h stores to the coherence point, then publish.
        __builtin_amdgcn_s_waitcnt(0);   // vmcnt(0) lgkmcnt(0) expcnt(0)
        __syncthreads();
        if (tid == 0)
            __hip_atomic_store(cnt + w, (unsigned)t, __ATOMIC_RELAXED,
                               __HIP_MEMORY_SCOPE_AGENT);
    }
}

// ---------------------------------------------------------------------------
extern "C" void kernel_launch(void* const* d_in, const int* in_sizes, int n_in,
                              void* d_out, int out_size, void* d_ws, size_t ws_size,
                              hipStream_t stream) {
    const float* x    = (const float*)d_in[0];  // [T,B,D]
    const float* z    = (const float*)d_in[1];  // [T,B,D]
    const float* h0   = (const float*)d_in[2];  // [B,D]
    const float* Wx   = (const float*)d_in[3];  // [D,D]
    const float* Wh   = (const float*)d_in[4];  // [D,D]
    const float* bias = (const float*)d_in[5];  // [D]
    float* out = (float*)d_out;

    // ws layout: xp 83.9 MB | hist (TT+1 steps) 84.0 MB | counters 1 KB
    float*    xp   = (float*)d_ws;
    float*    hist = xp + (size_t)TT * BB * DD;
    unsigned* cnt  = (unsigned*)(hist + (size_t)(TT + 1) * BB * DD);

    hipMemsetAsync(cnt, 0, 256 * sizeof(unsigned), stream);
    hipMemcpyAsync(hist, h0, (size_t)BB * DD * sizeof(float),
                   hipMemcpyDeviceToDevice, stream);  // hist[0] = h_0

    dim3 ggrid(DD / 64, (TT * BB) / 64);  // (20, 256)
    xproj_gemm<<<ggrid, 256, 0, stream>>>(x, Wx, bias, xp);
    gated_scan<<<256, 256, 0, stream>>>(xp, z, Wh, out, hist, cnt);
}

// Round 4
// 4858.672 us; speedup vs baseline: 2.0081x; 1.0832x over previous
//
#include <hip/hip_runtime.h>
#include <math.h>

#define TT 512
#define BB 32
#define DD 1280

// ---------------------------------------------------------------------------
// Kernel 1: x-projection GEMM.  XP[m][n] = bias[n] + sum_k X[m][k]*Wx[n][k]
// M = T*B = 16384, N = K = D = 1280.  fp32 (no fp32 MFMA on CDNA4).
// Unchanged from R1 (~700 us, ~77 TF; revisit after the scan).
// ---------------------------------------------------------------------------
__launch_bounds__(256) __global__
void xproj_gemm(const float* __restrict__ X, const float* __restrict__ Wx,
                const float* __restrict__ bias, float* __restrict__ XP)
{
    __shared__ __align__(16) float As[16][64];
    __shared__ __align__(16) float Bs[16][64];
    const int tid = threadIdx.x;
    const int n0 = blockIdx.x * 64;
    const int m0 = blockIdx.y * 64;
    const int lm = tid >> 2;
    const int lk = (tid & 3) << 2;
    const int tn = tid & 15;
    const int tm = tid >> 4;

    float acc[4][4] = {};
    for (int k0 = 0; k0 < DD; k0 += 16) {
        float4 av = *(const float4*)(X  + (size_t)(m0 + lm) * DD + k0 + lk);
        float4 bv = *(const float4*)(Wx + (size_t)(n0 + lm) * DD + k0 + lk);
        __syncthreads();
        As[lk + 0][lm] = av.x; As[lk + 1][lm] = av.y;
        As[lk + 2][lm] = av.z; As[lk + 3][lm] = av.w;
        Bs[lk + 0][lm] = bv.x; Bs[lk + 1][lm] = bv.y;
        Bs[lk + 2][lm] = bv.z; Bs[lk + 3][lm] = bv.w;
        __syncthreads();
#pragma unroll
        for (int k = 0; k < 16; ++k) {
            float4 a4 = *(const float4*)&As[k][tm << 2];
            float4 b4 = *(const float4*)&Bs[k][tn << 2];
            float a[4] = {a4.x, a4.y, a4.z, a4.w};
            float b[4] = {b4.x, b4.y, b4.z, b4.w};
#pragma unroll
            for (int i = 0; i < 4; ++i)
#pragma unroll
                for (int j = 0; j < 4; ++j)
                    acc[i][j] += a[i] * b[j];
        }
    }
    float4 bv = *(const float4*)(bias + n0 + (tn << 2));
    float bias4[4] = {bv.x, bv.y, bv.z, bv.w};
#pragma unroll
    for (int i = 0; i < 4; ++i) {
        float4 o;
        o.x = acc[i][0] + bias4[0];
        o.y = acc[i][1] + bias4[1];
        o.z = acc[i][2] + bias4[2];
        o.w = acc[i][3] + bias4[3];
        *(float4*)(XP + (size_t)(m0 + (tm << 2) + i) * DD + n0 + (tn << 2)) = o;
    }
}

// ---------------------------------------------------------------------------
// Device-scope (LLC-coherent) helpers: __hip_atomic_* AGENT scope -> sc1
// global ops, bypassing the non-coherent per-XCD L1/L2 (HW-validated R3).
// ---------------------------------------------------------------------------
__device__ __forceinline__ float4 ld_agent_f4(const float* p) {
    const unsigned long long* q = (const unsigned long long*)p;
    unsigned long long a = __hip_atomic_load(q + 0, __ATOMIC_RELAXED,
                                             __HIP_MEMORY_SCOPE_AGENT);
    unsigned long long b = __hip_atomic_load(q + 1, __ATOMIC_RELAXED,
                                             __HIP_MEMORY_SCOPE_AGENT);
    float4 v;
    v.x = __uint_as_float((unsigned)a);
    v.y = __uint_as_float((unsigned)(a >> 32));
    v.z = __uint_as_float((unsigned)b);
    v.w = __uint_as_float((unsigned)(b >> 32));
    return v;
}

// ---------------------------------------------------------------------------
// Kernel 2: persistent gated-Elman scan, write-once h history, LDS-staged.
//   4 batch-groups x 8 batches; 64 WGs/group, each owns 20 W_h rows.
//   LDS: W 102.4 KB + H stage 40 KB = 143.4 KB (1 WG/CU, grid 256 = #CUs,
//   all co-resident -> spins cannot deadlock).
//   R3 lesson: each WG re-read the same h 4x over the uncacheable sc1 path
//   (160 KB/WG/step from LLC).  R4: cooperative sc1 load of the UNIQUE
//   40 KB into LDS (10 float4/thread, one parallel LLC round-trip), then
//   the 4x reuse is served by LDS at 16B-stride (conflict-free, measured 0).
//   Sync protocol unchanged from R3 (HW-validated): per-WG monotonic
//   counters, sc1 publish after s_waitcnt(0)+barrier, sc1 polls.
// ---------------------------------------------------------------------------
__launch_bounds__(256, 1) __global__
void gated_scan(const float* __restrict__ XP, const float* __restrict__ Z,
                const float* __restrict__ Wh, float* __restrict__ OUT,
                float* __restrict__ hist, unsigned* __restrict__ cnt)
{
    const int w   = blockIdx.x;
    const int g   = w >> 6;       // batch group 0..3
    const int idx = w & 63;       // e-slice within group
    const int b0  = g << 3;       // first of 8 batches
    const int e0  = idx * 20;     // first of 20 W_h rows
    const int tid = threadIdx.x;
    const int u   = tid >> 5;     // 0..7
    const int p   = tid & 31;     // d-split lane
    const int bh  = u >> 2;       // 0..1 -> batches b0+4*bh+i
    const int eq  = u & 3;        // 0..3 -> e-rows e0+5*eq+j

    __shared__ __align__(16) float Wlds[20 * DD];   // 102.4 KB
    __shared__ __align__(16) float Hlds[8 * DD];    //  40.0 KB

    for (int i = tid; i < 20 * DD / 4; i += 256)
        ((float4*)Wlds)[i] = ((const float4*)(Wh + (size_t)e0 * DD))[i];
    __syncthreads();

    const int  o   = p;
    const bool fin = (p < 20);
    const int  bb  = b0 + (bh << 2) + o / 5;
    const int  ee  = e0 + eq * 5 + o % 5;

    for (int t = 1; t <= TT; ++t) {
        // prefetch xp/z (independent of h -> overlaps the wait)
        const size_t oidx = ((size_t)(t - 1) * BB + bb) * DD + ee;
        float xpv = 0.f, zv = 0.f;
        if (fin) { xpv = XP[oidx]; zv = Z[oidx]; }

        // wait for all 64 group peers to have published h_{t-1}
        if (tid < 64) {
            const unsigned  tgt = (unsigned)(t - 1);
            const unsigned* c   = cnt + (g << 6) + tid;
            while (__hip_atomic_load(c, __ATOMIC_RELAXED,
                                     __HIP_MEMORY_SCOPE_AGENT) < tgt) {}
        }
        __syncthreads();   // (A) poll done; Hlds of step t-1 fully consumed

        // cooperative coherent load of the group's unique h block (40 KB):
        // contiguous [8][1280] floats starting at hist[t-1][b0][0].
        const float* hsrc = hist + ((size_t)(t - 1) * BB + b0) * DD;
        float4 hs[10];
#pragma unroll
        for (int j = 0; j < 10; ++j)
            hs[j] = ld_agent_f4(hsrc + ((j << 8) + tid) * 4);
#pragma unroll
        for (int j = 0; j < 10; ++j)
            ((float4*)Hlds)[(j << 8) + tid] = hs[j];
        __syncthreads();   // (B) Hlds ready

        float acc[4][5] = {};
#pragma unroll
        for (int k = 0; k < 10; ++k) {
            const int d = (p << 2) + (k << 7);   // 4p + 128k
            float4 h4[4], w4[5];
#pragma unroll
            for (int i = 0; i < 4; ++i)
                h4[i] = *(const float4*)&Hlds[((bh << 2) + i) * DD + d];
#pragma unroll
            for (int j = 0; j < 5; ++j)
                w4[j] = *(const float4*)&Wlds[(eq * 5 + j) * DD + d];
#pragma unroll
            for (int i = 0; i < 4; ++i)
#pragma unroll
                for (int j = 0; j < 5; ++j)
                    acc[i][j] += h4[i].x * w4[j].x + h4[i].y * w4[j].y
                               + h4[i].z * w4[j].z + h4[i].w * w4[j].w;
        }

        // all-reduce over the 32 d-split lanes (bit5 = unit bit, untouched)
#pragma unroll
        for (int m = 16; m >= 1; m >>= 1)
#pragma unroll
            for (int i = 0; i < 4; ++i)
#pragma unroll
                for (int j = 0; j < 5; ++j)
                    acc[i][j] += __shfl_xor(acc[i][j], m, 64);

        if (fin) {
            float sum = acc[0][0];
#pragma unroll
            for (int q = 1; q < 20; ++q)
                sum = (o == q) ? acc[q / 5][q % 5] : sum;
            const float hn = tanhf(xpv + sum);
            const float sg = zv / (1.0f + __expf(-zv));
            OUT[oidx] = hn * sg;
            __hip_atomic_store(hist + (size_t)t * BB * DD +
                               (size_t)bb * DD + ee, hn,
                               __ATOMIC_RELAXED, __HIP_MEMORY_SCOPE_AGENT);
            if (t == TT)
                OUT[(size_t)TT * BB * DD + (size_t)bb * DD + ee] = hn;
        }
        // drain sc1 h stores to the coherence point, then publish.
        __builtin_amdgcn_s_waitcnt(0);   // vmcnt(0) lgkmcnt(0) expcnt(0)
        __syncthreads();   // (C)
        if (tid == 0)
            __hip_atomic_store(cnt + w, (unsigned)t, __ATOMIC_RELAXED,
                               __HIP_MEMORY_SCOPE_AGENT);
    }
}

// ---------------------------------------------------------------------------
extern "C" void kernel_launch(void* const* d_in, const int* in_sizes, int n_in,
                              void* d_out, int out_size, void* d_ws, size_t ws_size,
                              hipStream_t stream) {
    const float* x    = (const float*)d_in[0];  // [T,B,D]
    const float* z    = (const float*)d_in[1];  // [T,B,D]
    const float* h0   = (const float*)d_in[2];  // [B,D]
    const float* Wx   = (const float*)d_in[3];  // [D,D]
    const float* Wh   = (const float*)d_in[4];  // [D,D]
    const float* bias = (const float*)d_in[5];  // [D]
    float* out = (float*)d_out;

    // ws layout: xp 83.9 MB | hist (TT+1 steps) 84.0 MB | counters 1 KB
    float*    xp   = (float*)d_ws;
    float*    hist = xp + (size_t)TT * BB * DD;
    unsigned* cnt  = (unsigned*)(hist + (size_t)(TT + 1) * BB * DD);

    hipMemsetAsync(cnt, 0, 256 * sizeof(unsigned), stream);
    hipMemcpyAsync(hist, h0, (size_t)BB * DD * sizeof(float),
                   hipMemcpyDeviceToDevice, stream);  // hist[0] = h_0

    dim3 ggrid(DD / 64, (TT * BB) / 64);  // (20, 256)
    xproj_gemm<<<ggrid, 256, 0, stream>>>(x, Wx, bias, xp);
    gated_scan<<<256, 256, 0, stream>>>(xp, z, Wh, out, hist, cnt);
}